// Round 8
// baseline (3457.575 us; speedup 1.0000x reference)
//
#include <hip/hip_runtime.h>
#include <hip/hip_bf16.h>
#include <hip/hip_cooperative_groups.h>
#include <math.h>

namespace cg = cooperative_groups;

// DAGNN r17:
//  - base = r11 (best measured 980us): fused-pooling hop, r11 mlp (84us),
//    r11 build passes.
//  - spmm: ONE cooperative persistent kernel does all 10 hops with
//    grid.sync() between them (removes 9 launch/drain boundaries + per-hop
//    25000-block dispatch ramp). Wave owns ~13 contiguous dests; ping-pong
//    gA/gB by hop parity. Inner loop verbatim from r11 (proven).
//  - passD also emits dinv (dinv_kernel dropped).
//  - Lessons kept: hop is random-line-service bound (~78us irreducible);
//    no src-range split, no LDS atomics, no channel planes, no deferred pool.

#define WAVE 64
#define NBLK 1024   // blocks in passA/passB; must match between them
#define RS 520      // LDS region stride in ushorts (64*8 + 8 pad)

__device__ inline float bf2f(unsigned short u) {
    union { unsigned int i; float f; } v; v.i = ((unsigned int)u) << 16; return v.f;
}
__device__ inline unsigned short f2bf(float f) {
    __hip_bfloat16 b = __float2bfloat16(f);
    union { __hip_bfloat16 b; unsigned short u; } v; v.b = b; return v.u;
}
__device__ inline float bflo(unsigned u) {
    union { unsigned i; float f; } v; v.i = u << 16; return v.f;
}
__device__ inline float bfhi(unsigned u) {
    union { unsigned i; float f; } v; v.i = u & 0xffff0000u; return v.f;
}

typedef __attribute__((ext_vector_type(8))) short bf16x8;
typedef __attribute__((ext_vector_type(16))) float f32x16;

// ---- edge dtype detection: stride 1 (int32) or 2 (int64 low words) ----
__global__ void detect_kernel(const unsigned* __restrict__ e, int* __restrict__ sflag) {
    __shared__ int any;
    if (threadIdx.x == 0) any = 0;
    __syncthreads();
    unsigned nz = 0;
    int t = threadIdx.x;
    for (int i = 0; i < 8; ++i) nz |= e[(size_t)(t * 8 + i) * 2 + 1];
    if (nz) atomicOr(&any, 1);
    __syncthreads();
    if (t == 0) *sflag = any ? 1 : 2;
}

// ---- passA: per-block LDS bucket histogram; blk_cnt[blk][bucket] ----
__global__ void passA_kernel(const int* __restrict__ eidx, const int* __restrict__ sflag,
                             int* __restrict__ blk_cnt, int E, int NB, int EPB) {
    __shared__ int lh[512];
    int t = threadIdx.x, blk = blockIdx.x;
    for (int i = t; i < NB; i += 256) lh[i] = 0;
    __syncthreads();
    int s = *sflag;
    int base = blk * EPB;
    int end = base + EPB; if (end > E) end = E;
    for (int e = base + t; e < end; e += 256) {
        int c = eidx[(size_t)s * (size_t)(E + e)];
        atomicAdd(&lh[c >> 8], 1);
    }
    __syncthreads();
    for (int i = t; i < NB; i += 256)
        blk_cnt[(size_t)blk * NB + i] = lh[i];
}

// ---- scans ----
__global__ void scan1_kernel(const int* __restrict__ in, int* __restrict__ out,
                             int* __restrict__ bsums, int n) {
    __shared__ int s[256];
    int t = threadIdx.x;
    int idx = blockIdx.x * 1024 + t * 4;
    int x0 = (idx + 0 < n) ? in[idx + 0] : 0;
    int x1 = (idx + 1 < n) ? in[idx + 1] : 0;
    int x2 = (idx + 2 < n) ? in[idx + 2] : 0;
    int x3 = (idx + 3 < n) ? in[idx + 3] : 0;
    int lsum = x0 + x1 + x2 + x3;
    s[t] = lsum;
    __syncthreads();
    for (int o = 1; o < 256; o <<= 1) {
        int v = (t >= o) ? s[t - o] : 0;
        __syncthreads();
        if (t >= o) s[t] += v;
        __syncthreads();
    }
    int excl = s[t] - lsum;
    if (idx + 0 < n) out[idx + 0] = excl;
    if (idx + 1 < n) out[idx + 1] = excl + x0;
    if (idx + 2 < n) out[idx + 2] = excl + x0 + x1;
    if (idx + 3 < n) out[idx + 3] = excl + x0 + x1 + x2;
    if (t == 255) bsums[blockIdx.x] = s[255];
}

__global__ void scan2g_kernel(int* __restrict__ bsums, int nb) {
    __shared__ int part[256];
    int t = threadIdx.x;
    int v[4]; int run = 0;
    #pragma unroll
    for (int j = 0; j < 4; ++j) {
        int i = t * 4 + j;
        int x = (i < nb) ? bsums[i] : 0;
        v[j] = run; run += x;
    }
    part[t] = run;
    __syncthreads();
    for (int o = 1; o < 256; o <<= 1) {
        int x = (t >= o) ? part[t - o] : 0;
        __syncthreads();
        if (t >= o) part[t] += x;
        __syncthreads();
    }
    int excl = part[t] - run;
    #pragma unroll
    for (int j = 0; j < 4; ++j) {
        int i = t * 4 + j;
        if (i < nb) bsums[i] = excl + v[j];
    }
}

__global__ void scan3_kernel(int* __restrict__ arr, const int* __restrict__ bsums,
                             int n, int total) {
    int t = threadIdx.x;
    int idx = blockIdx.x * 1024 + t * 4;
    int add = bsums[blockIdx.x];
    #pragma unroll
    for (int i = 0; i < 4; ++i)
        if (idx + i < n) arr[idx + i] += add;
    if (blockIdx.x == 0 && t == 0) arr[n] = total;
}

// ---- passB: LDS-cursor pair scatter; windows block-major (dense per block) ----
__global__ void passB_kernel(const int* __restrict__ eidx, const int* __restrict__ sflag,
                             const int* __restrict__ pbase, int2* __restrict__ pairs,
                             int E, int NB, int EPB) {
    __shared__ int lcur[512];
    int t = threadIdx.x, blk = blockIdx.x;
    for (int i = t; i < NB; i += 256) lcur[i] = pbase[(size_t)blk * NB + i];
    __syncthreads();
    int s = *sflag;
    int base = blk * EPB;
    int end = base + EPB; if (end > E) end = E;
    for (int e = base + t; e < end; e += 256) {
        int r = eidx[(size_t)s * (size_t)e];
        int c = eidx[(size_t)s * (size_t)(E + e)];
        int pos = atomicAdd(&lcur[c >> 8], 1);
        pairs[pos] = make_int2(r, c);
    }
}

// ---- passD: per-bucket node degree counts + dinv; windows at pbase[blk*NB+b] ----
__global__ void passD_kernel(const int2* __restrict__ pairs, const int* __restrict__ pbase,
                             int* __restrict__ cnt, float* __restrict__ dinv,
                             int N, int NB) {
    __shared__ int lcnt[256];
    int b = blockIdx.x, t = threadIdx.x;
    lcnt[t] = 0;
    __syncthreads();
    for (int blk = t; blk < NBLK; blk += 256) {
        int w0 = pbase[(size_t)blk * NB + b];
        int w1 = pbase[(size_t)blk * NB + b + 1];
        for (int i = w0; i < w1; ++i)
            atomicAdd(&lcnt[pairs[i].y & 255], 1);
    }
    __syncthreads();
    int node = b * 256 + t;
    if (node < N) {
        cnt[node] = lcnt[t];
        dinv[node] = rsqrtf((float)(lcnt[t] + 1));   // self-loop adds 1
    }
}

// ---- passC: per-bucket LDS cursors, scatter src into final CSR window ----
__global__ void passC_kernel(const int2* __restrict__ pairs, const int* __restrict__ pbase,
                             const int* __restrict__ offs, int* __restrict__ csr_src,
                             int N, int NB) {
    __shared__ int lcur[256];
    int b = blockIdx.x, t = threadIdx.x;
    int node = b * 256 + t;
    lcur[t] = (node < N) ? offs[node] : 0;
    __syncthreads();
    for (int blk = t; blk < NBLK; blk += 256) {
        int w0 = pbase[(size_t)blk * NB + b];
        int w1 = pbase[(size_t)blk * NB + b + 1];
        for (int i = w0; i < w1; ++i) {
            int2 p = pairs[i];
            int pos = atomicAdd(&lcur[p.y & 255], 1);
            csr_src[pos] = p.x;
        }
    }
}

// ---- weight convert to fragment-major: Wf[(k>>3)*Nn*8 + n*8 + (k&7)] = bf16(W[k][n]) ----
__global__ void wconv_kernel(const float* __restrict__ W, unsigned short* __restrict__ Wf,
                             int K, int Nn) {
    int i = blockIdx.x * blockDim.x + threadIdx.x;
    if (i >= K * Nn) return;
    int k = i / Nn, n = i - k * Nn;
    Wf[(size_t)(k >> 3) * Nn * 8 + n * 8 + (k & 7)] = f2bf(W[i]);
}

// ---- fused MLP (r11 form): h = relu(x@W1+b1)@W2+b2 ; out = sigmoid(h.pw+pb)*h ;
//      g0 = bf16(dinv*h).  BM=64 rows/block, 256 thr (4 waves). ----
__global__ __launch_bounds__(256, 4) void mlp_fused(
        const float* __restrict__ x,
        const unsigned short* __restrict__ W1f,   // frag-major [k>>3][256 n][8]
        const float* __restrict__ b1,
        const unsigned short* __restrict__ W2f,   // frag-major [k>>3][64 n][8]
        const float* __restrict__ b2,
        const float* __restrict__ dinv,
        const float* __restrict__ pw, const float* __restrict__ pb,
        float* __restrict__ out, unsigned short* __restrict__ g,
        int M) {
    __shared__ unsigned short xfrag[4 * RS];    // region = (k&31)>>3
    __shared__ unsigned short h1frag[32 * RS];  // region = ch>>3 (stage-2 k)
    __shared__ float pools[2][2][2][16];        // [rt2][ct2][half][reg]

    int tid = threadIdx.x;
    int wave = tid >> 6, lane = tid & 63;
    int half = lane >> 5, l31 = lane & 31;
    int rt = wave & 1;          // stage-1 row tile (32 rows)
    int cw = wave >> 1;         // stage-1 col half (128 cols)
    int bm = blockIdx.x * 64;

    f32x16 acc1[4] = {};

    float4 xv[2];
    #pragma unroll
    for (int i = 0; i < 2; ++i) {
        int f = i * 256 + tid;
        int row = f >> 3, c4 = (f & 7) * 4;
        int grow = bm + row;
        xv[i] = (grow < M) ? *(const float4*)(x + (size_t)grow * 256 + c4)
                           : make_float4(0.f, 0.f, 0.f, 0.f);
    }

    for (int it = 0; it < 8; ++it) {
        #pragma unroll
        for (int i = 0; i < 2; ++i) {
            int f = i * 256 + tid;
            int row = f >> 3, c4 = (f & 7) * 4;
            int region = c4 >> 3, off = c4 & 7;
            ushort4 u;
            u.x = f2bf(xv[i].x); u.y = f2bf(xv[i].y);
            u.z = f2bf(xv[i].z); u.w = f2bf(xv[i].w);
            *(ushort4*)&xfrag[region * RS + row * 8 + off] = u;
        }
        __syncthreads();
        if (it < 7) {
            int k0 = (it + 1) * 32;
            #pragma unroll
            for (int i = 0; i < 2; ++i) {
                int f = i * 256 + tid;
                int row = f >> 3, c4 = (f & 7) * 4;
                int grow = bm + row;
                xv[i] = (grow < M) ? *(const float4*)(x + (size_t)grow * 256 + k0 + c4)
                                   : make_float4(0.f, 0.f, 0.f, 0.f);
            }
        }
        // MFMAs; B fragments coalesced from global frag-major layout
        #pragma unroll
        for (int s = 0; s < 2; ++s) {
            int region = it * 4 + s * 2 + half;          // k>>3 of this fragment
            bf16x8 a = *(bf16x8*)&xfrag[(s * 2 + half) * RS + (rt * 32 + l31) * 8];
            #pragma unroll
            for (int j = 0; j < 4; ++j) {
                int ch = cw * 128 + j * 32 + l31;
                bf16x8 b = *(const bf16x8*)(W1f + (size_t)region * 2048 + ch * 8);
                acc1[j] = __builtin_amdgcn_mfma_f32_32x32x16_bf16(a, b, acc1[j], 0, 0, 0);
            }
        }
        __syncthreads();
    }

    // bias + relu, write h1 tile to LDS in stage-2 A-fragment layout
    #pragma unroll
    for (int j = 0; j < 4; ++j) {
        int ch = cw * 128 + j * 32 + l31;     // stage-2 k index
        float bb = b1[ch];
        int region = ch >> 3, off = ch & 7;
        #pragma unroll
        for (int reg = 0; reg < 16; ++reg) {
            int rowin = (reg & 3) + 8 * (reg >> 2) + 4 * half;
            int row = rt * 32 + rowin;
            float v = fmaxf(acc1[j][reg] + bb, 0.f);
            h1frag[region * RS + row * 8 + off] = f2bf(v);
        }
    }
    __syncthreads();

    // stage 2 on all 4 waves: wave = rt2*2 + ct2 tile (32 rows x 32 cols)
    int rt2 = wave >> 1, ct2 = wave & 1;
    f32x16 acc2 = {};
    #pragma unroll
    for (int s = 0; s < 16; ++s) {
        bf16x8 a = *(bf16x8*)&h1frag[(s * 2 + half) * RS + (rt2 * 32 + l31) * 8];
        bf16x8 b = *(const bf16x8*)(W2f + (size_t)(s * 2 + half) * 512 + (ct2 * 32 + l31) * 8);
        acc2 = __builtin_amdgcn_mfma_f32_32x32x16_bf16(a, b, acc2, 0, 0, 0);
    }

    // pooling partials: butterfly over 32 cols, pool-exchange across col tiles
    float bb = b2[ct2 * 32 + l31];
    float pwv = pw[ct2 * 32 + l31];
    float pbv = pb[0];
    float hreg[16];
    #pragma unroll
    for (int reg = 0; reg < 16; ++reg) {
        float h = acc2[reg] + bb;
        hreg[reg] = h;
        float d = h * pwv;
        d += __shfl_xor(d, 1, 64);
        d += __shfl_xor(d, 2, 64);
        d += __shfl_xor(d, 4, 64);
        d += __shfl_xor(d, 8, 64);
        d += __shfl_xor(d, 16, 64);
        if (l31 == 0) pools[rt2][ct2][half][reg] = d;
    }
    __syncthreads();
    #pragma unroll
    for (int reg = 0; reg < 16; ++reg) {
        int rowin = (reg & 3) + 8 * (reg >> 2) + 4 * half;
        int row = bm + rt2 * 32 + rowin;
        float d = pools[rt2][0][half][reg] + pools[rt2][1][half][reg];
        float sg = 1.f / (1.f + __expf(-(d + pbv)));
        float h = hreg[reg];
        if (row < M) {
            float dv = dinv[row];
            out[(size_t)row * 64 + ct2 * 32 + l31] = sg * h;
            g[(size_t)row * 64 + ct2 * 32 + l31]   = f2bf(dv * h);
        }
    }
}

// ---- all 10 hops in ONE cooperative kernel (r11 inner loop verbatim).
//      Wave owns dpw contiguous dests; grid.sync() between hops;
//      ping-pong gA/gB by hop parity; fused pooling + out RMW. ----
__global__ __launch_bounds__(256) void spmm_coop(
        const int* __restrict__ offs, const int* __restrict__ src,
        const float* __restrict__ dinv,
        unsigned* __restrict__ gA, unsigned* __restrict__ gB,
        float* __restrict__ out,
        const float* __restrict__ pw, const float* __restrict__ pb,
        int n, int dpw) {
    cg::grid_group grid = cg::this_grid();
    int gw = (blockIdx.x * blockDim.x + threadIdx.x) >> 6;
    int lane = threadIdx.x & 63;
    int g = lane >> 4;      // edge slot within a quad (0..3)
    int q = lane & 15;      // word-pair index -> channels 4q..4q+3
    float4 pv = *(const float4*)(pw + q * 4);
    float pbv = pb[0];
    int base = gw * dpw;

    for (int k = 0; k < 10; ++k) {
        const unsigned* gin = (k & 1) ? gB : gA;
        unsigned* gout = (k & 1) ? gA : gB;
        for (int j = 0; j < dpw; ++j) {
            int c = base + j;
            if (c < n) {
                int e0 = __builtin_amdgcn_readfirstlane(offs[c]);
                int eend = __builtin_amdgcn_readfirstlane(offs[c + 1]);
                float a0 = 0.f, a1 = 0.f, a2 = 0.f, a3 = 0.f;
                for (int e = e0; e < eend; e += 32) {
                    #pragma unroll
                    for (int i = 0; i < 8; ++i) {
                        int ei = e + i * 4 + g;
                        int ec = (ei < eend) ? ei : (eend - 1);
                        float m = (ei < eend) ? 1.f : 0.f;
                        int s = src[ec];
                        uint2 v = *(const uint2*)(gin + (size_t)s * 32 + q * 2);
                        a0 = fmaf(m, bflo(v.x), a0);
                        a1 = fmaf(m, bfhi(v.x), a1);
                        a2 = fmaf(m, bflo(v.y), a2);
                        a3 = fmaf(m, bfhi(v.y), a3);
                    }
                }
                // reduce across the 4 edge slots (xor 16, 32 stay within q)
                a0 += __shfl_xor(a0, 16, 64); a0 += __shfl_xor(a0, 32, 64);
                a1 += __shfl_xor(a1, 16, 64); a1 += __shfl_xor(a1, 32, 64);
                a2 += __shfl_xor(a2, 16, 64); a2 += __shfl_xor(a2, 32, 64);
                a3 += __shfl_xor(a3, 16, 64); a3 += __shfl_xor(a3, 32, 64);

                // self-loop term (gin already prescaled by dinv[src])
                uint2 sv = *(const uint2*)(gin + (size_t)c * 32 + q * 2);
                a0 += bflo(sv.x); a1 += bfhi(sv.x);
                a2 += bflo(sv.y); a3 += bfhi(sv.y);

                float dc = dinv[c];
                float h0 = dc * a0, h1 = dc * a1, h2 = dc * a2, h3 = dc * a3;

                // fused adaptive pooling
                float d = h0 * pv.x + h1 * pv.y + h2 * pv.z + h3 * pv.w;
                d += __shfl_xor(d, 1, 64);
                d += __shfl_xor(d, 2, 64);
                d += __shfl_xor(d, 4, 64);
                d += __shfl_xor(d, 8, 64);
                float sg = 1.f / (1.f + __expf(-(d + pbv)));

                if (g == 0) {
                    unsigned g0 = (unsigned)f2bf(dc * h0) | ((unsigned)f2bf(dc * h1) << 16);
                    unsigned g1 = (unsigned)f2bf(dc * h2) | ((unsigned)f2bf(dc * h3) << 16);
                    *(uint2*)(gout + (size_t)c * 32 + q * 2) = make_uint2(g0, g1);
                    float4 o = *(float4*)(out + (size_t)c * 64 + q * 4);
                    o.x += sg * h0; o.y += sg * h1;
                    o.z += sg * h2; o.w += sg * h3;
                    *(float4*)(out + (size_t)c * 64 + q * 4) = o;
                }
            }
        }
        if (k < 9) {
            __threadfence();
            grid.sync();
        }
    }
}

extern "C" void kernel_launch(void* const* d_in, const int* in_sizes, int n_in,
                              void* d_out, int out_size, void* d_ws, size_t ws_size,
                              hipStream_t stream) {
    const float* x  = (const float*)d_in[0];
    const int* eidx = (const int*)d_in[1];
    const float* W1 = (const float*)d_in[2];
    const float* b1 = (const float*)d_in[3];
    const float* W2 = (const float*)d_in[4];
    const float* b2 = (const float*)d_in[5];
    const float* pw = (const float*)d_in[6];
    const float* pb = (const float*)d_in[7];
    float* out = (float*)d_out;

    const int N = in_sizes[0] / 256;
    const int E = in_sizes[1] / 2;
    const int NB = (N + 255) >> 8;              // buckets of 256 dest nodes
    const int EPB = (E + NBLK - 1) / NBLK;      // edges per passA/passB block
    const int M = NB * NBLK;                    // blk_cnt entries

    size_t woff = 0;
    auto alloc = [&](size_t bytes) -> void* {
        void* p = (char*)d_ws + woff;
        woff += (bytes + 255) & ~(size_t)255;
        return p;
    };
    int*   sflag   = (int*)alloc(4);
    int*   cnt     = (int*)alloc((size_t)N * 4);
    float* dinv    = (float*)alloc((size_t)N * 4);
    int*   offs    = (int*)alloc(((size_t)N + 1) * 4);
    int*   bsums   = (int*)alloc(1024 * 4);
    int*   bsums2  = (int*)alloc(1024 * 4);
    int*   pbase   = (int*)alloc(((size_t)M + 1) * 4);
    int*   csr_src = (int*)alloc((size_t)E * 4);
    int2*  pairs   = (int2*)alloc((size_t)E * 8);
    unsigned short* W1f = (unsigned short*)alloc((size_t)256 * 256 * 2);
    unsigned short* W2f = (unsigned short*)alloc((size_t)64 * 256 * 2);
    unsigned short* gA = (unsigned short*)alloc((size_t)N * 64 * 2);
    unsigned short* gB = (unsigned short*)alloc((size_t)N * 64 * 2);

    detect_kernel<<<1, 256, 0, stream>>>((const unsigned*)eidx, sflag);

    // build: histogram -> scan -> pair scatter -> node counts(+dinv) -> offs -> CSR
    passA_kernel<<<NBLK, 256, 0, stream>>>(eidx, sflag, pbase, E, NB, EPB);
    int nb2 = (M + 1023) / 1024;
    scan1_kernel<<<nb2, 256, 0, stream>>>(pbase, pbase, bsums2, M);
    scan2g_kernel<<<1, 256, 0, stream>>>(bsums2, nb2);
    scan3_kernel<<<nb2, 256, 0, stream>>>(pbase, bsums2, M, E);
    passB_kernel<<<NBLK, 256, 0, stream>>>(eidx, sflag, pbase, pairs, E, NB, EPB);
    passD_kernel<<<NB, 256, 0, stream>>>(pairs, pbase, cnt, dinv, N, NB);
    int nb1 = (N + 1023) / 1024;
    scan1_kernel<<<nb1, 256, 0, stream>>>(cnt, offs, bsums, N);
    scan2g_kernel<<<1, 256, 0, stream>>>(bsums, nb1);
    scan3_kernel<<<nb1, 256, 0, stream>>>(offs, bsums, N, E);
    passC_kernel<<<NB, 256, 0, stream>>>(pairs, pbase, offs, csr_src, N, NB);

    // MLP (fused) + hop0
    wconv_kernel<<<(256 * 256 + 255) / 256, 256, 0, stream>>>(W1, W1f, 256, 256);
    wconv_kernel<<<(64 * 256 + 255) / 256, 256, 0, stream>>>(W2, W2f, 256, 64);
    int gb = (N + 63) / 64;
    mlp_fused<<<gb, 256, 0, stream>>>(x, W1f, b1, W2f, b2, dinv, pw, pb,
                                      out, gA, N);

    // propagation: all 10 hops in one cooperative persistent kernel
    static int coop_grid = 0;
    if (coop_grid == 0) {
        int nbpc = 0;
        hipError_t err = hipOccupancyMaxActiveBlocksPerMultiprocessor(
            &nbpc, (const void*)spmm_coop, 256, 0);
        if (err != hipSuccess || nbpc <= 0) nbpc = 4;   // conservative fallback
        coop_grid = nbpc * 256;                         // 256 CUs on MI355X
    }
    int nwaves = coop_grid * 4;
    int dpw = (N + nwaves - 1) / nwaves;
    unsigned* gAu = (unsigned*)gA;
    unsigned* gBu = (unsigned*)gB;
    int Nv = N;
    void* args[] = { (void*)&offs, (void*)&csr_src, (void*)&dinv,
                     (void*)&gAu, (void*)&gBu, (void*)&out,
                     (void*)&pw, (void*)&pb, (void*)&Nv, (void*)&dpw };
    hipLaunchCooperativeKernel((const void*)spmm_coop, dim3(coop_grid), dim3(256),
                               args, 0, stream);
}

// Round 9
// 978.150 us; speedup vs baseline: 3.5348x; 3.5348x over previous
//
#include <hip/hip_runtime.h>
#include <hip/hip_bf16.h>
#include <math.h>

// DAGNN r18 = r11 (best measured: 980us) + passD/dinv fusion.
//  - spmm: wave per dest, 16 lanes/row (uint2 = 4 ch/lane), 4 edges per
//    gather instruction, 32 edges in flight; fused adaptive pooling + out RMW.
//    PROVEN at ~78-80us/hop = 410 MB random 128B-line gather at ~5.3 TB/s
//    effective (~84% of streaming ceiling). Six structural alternatives
//    (r12 range sweep, r13 bucket-LDS, r14 channel planes, r15 deferred pool,
//    r16 monolithic mlp load, r17 cooperative persistence) all regressed or
//    were neutral -- this is the practical roofline for the hop.
//  - mlp_fused: r11 form (8-iter pipelined staging; r16's single-phase load
//    serialized the latency chain and regressed 77->92us).
//  - build: r11 passes, dinv fused into passD.

#define WAVE 64
#define NBLK 1024   // blocks in passA/passB; must match between them
#define RS 520      // LDS region stride in ushorts (64*8 + 8 pad)

__device__ inline float bf2f(unsigned short u) {
    union { unsigned int i; float f; } v; v.i = ((unsigned int)u) << 16; return v.f;
}
__device__ inline unsigned short f2bf(float f) {
    __hip_bfloat16 b = __float2bfloat16(f);
    union { __hip_bfloat16 b; unsigned short u; } v; v.b = b; return v.u;
}
__device__ inline float bflo(unsigned u) {
    union { unsigned i; float f; } v; v.i = u << 16; return v.f;
}
__device__ inline float bfhi(unsigned u) {
    union { unsigned i; float f; } v; v.i = u & 0xffff0000u; return v.f;
}

typedef __attribute__((ext_vector_type(8))) short bf16x8;
typedef __attribute__((ext_vector_type(16))) float f32x16;

// ---- edge dtype detection: stride 1 (int32) or 2 (int64 low words) ----
__global__ void detect_kernel(const unsigned* __restrict__ e, int* __restrict__ sflag) {
    __shared__ int any;
    if (threadIdx.x == 0) any = 0;
    __syncthreads();
    unsigned nz = 0;
    int t = threadIdx.x;
    for (int i = 0; i < 8; ++i) nz |= e[(size_t)(t * 8 + i) * 2 + 1];
    if (nz) atomicOr(&any, 1);
    __syncthreads();
    if (t == 0) *sflag = any ? 1 : 2;
}

// ---- passA: per-block LDS bucket histogram; blk_cnt[blk][bucket] ----
__global__ void passA_kernel(const int* __restrict__ eidx, const int* __restrict__ sflag,
                             int* __restrict__ blk_cnt, int E, int NB, int EPB) {
    __shared__ int lh[512];
    int t = threadIdx.x, blk = blockIdx.x;
    for (int i = t; i < NB; i += 256) lh[i] = 0;
    __syncthreads();
    int s = *sflag;
    int base = blk * EPB;
    int end = base + EPB; if (end > E) end = E;
    for (int e = base + t; e < end; e += 256) {
        int c = eidx[(size_t)s * (size_t)(E + e)];
        atomicAdd(&lh[c >> 8], 1);
    }
    __syncthreads();
    for (int i = t; i < NB; i += 256)
        blk_cnt[(size_t)blk * NB + i] = lh[i];
}

// ---- scans ----
__global__ void scan1_kernel(const int* __restrict__ in, int* __restrict__ out,
                             int* __restrict__ bsums, int n) {
    __shared__ int s[256];
    int t = threadIdx.x;
    int idx = blockIdx.x * 1024 + t * 4;
    int x0 = (idx + 0 < n) ? in[idx + 0] : 0;
    int x1 = (idx + 1 < n) ? in[idx + 1] : 0;
    int x2 = (idx + 2 < n) ? in[idx + 2] : 0;
    int x3 = (idx + 3 < n) ? in[idx + 3] : 0;
    int lsum = x0 + x1 + x2 + x3;
    s[t] = lsum;
    __syncthreads();
    for (int o = 1; o < 256; o <<= 1) {
        int v = (t >= o) ? s[t - o] : 0;
        __syncthreads();
        if (t >= o) s[t] += v;
        __syncthreads();
    }
    int excl = s[t] - lsum;
    if (idx + 0 < n) out[idx + 0] = excl;
    if (idx + 1 < n) out[idx + 1] = excl + x0;
    if (idx + 2 < n) out[idx + 2] = excl + x0 + x1;
    if (idx + 3 < n) out[idx + 3] = excl + x0 + x1 + x2;
    if (t == 255) bsums[blockIdx.x] = s[255];
}

__global__ void scan2g_kernel(int* __restrict__ bsums, int nb) {
    __shared__ int part[256];
    int t = threadIdx.x;
    int v[4]; int run = 0;
    #pragma unroll
    for (int j = 0; j < 4; ++j) {
        int i = t * 4 + j;
        int x = (i < nb) ? bsums[i] : 0;
        v[j] = run; run += x;
    }
    part[t] = run;
    __syncthreads();
    for (int o = 1; o < 256; o <<= 1) {
        int x = (t >= o) ? part[t - o] : 0;
        __syncthreads();
        if (t >= o) part[t] += x;
        __syncthreads();
    }
    int excl = part[t] - run;
    #pragma unroll
    for (int j = 0; j < 4; ++j) {
        int i = t * 4 + j;
        if (i < nb) bsums[i] = excl + v[j];
    }
}

__global__ void scan3_kernel(int* __restrict__ arr, const int* __restrict__ bsums,
                             int n, int total) {
    int t = threadIdx.x;
    int idx = blockIdx.x * 1024 + t * 4;
    int add = bsums[blockIdx.x];
    #pragma unroll
    for (int i = 0; i < 4; ++i)
        if (idx + i < n) arr[idx + i] += add;
    if (blockIdx.x == 0 && t == 0) arr[n] = total;
}

// ---- passB: LDS-cursor pair scatter; windows block-major (dense per block) ----
__global__ void passB_kernel(const int* __restrict__ eidx, const int* __restrict__ sflag,
                             const int* __restrict__ pbase, int2* __restrict__ pairs,
                             int E, int NB, int EPB) {
    __shared__ int lcur[512];
    int t = threadIdx.x, blk = blockIdx.x;
    for (int i = t; i < NB; i += 256) lcur[i] = pbase[(size_t)blk * NB + i];
    __syncthreads();
    int s = *sflag;
    int base = blk * EPB;
    int end = base + EPB; if (end > E) end = E;
    for (int e = base + t; e < end; e += 256) {
        int r = eidx[(size_t)s * (size_t)e];
        int c = eidx[(size_t)s * (size_t)(E + e)];
        int pos = atomicAdd(&lcur[c >> 8], 1);
        pairs[pos] = make_int2(r, c);
    }
}

// ---- passD: per-bucket node degree counts + dinv; windows at pbase[blk*NB+b] ----
__global__ void passD_kernel(const int2* __restrict__ pairs, const int* __restrict__ pbase,
                             int* __restrict__ cnt, float* __restrict__ dinv,
                             int N, int NB) {
    __shared__ int lcnt[256];
    int b = blockIdx.x, t = threadIdx.x;
    lcnt[t] = 0;
    __syncthreads();
    for (int blk = t; blk < NBLK; blk += 256) {
        int w0 = pbase[(size_t)blk * NB + b];
        int w1 = pbase[(size_t)blk * NB + b + 1];
        for (int i = w0; i < w1; ++i)
            atomicAdd(&lcnt[pairs[i].y & 255], 1);
    }
    __syncthreads();
    int node = b * 256 + t;
    if (node < N) {
        cnt[node] = lcnt[t];
        dinv[node] = rsqrtf((float)(lcnt[t] + 1));   // self-loop adds 1
    }
}

// ---- passC: per-bucket LDS cursors, scatter src into final CSR window ----
__global__ void passC_kernel(const int2* __restrict__ pairs, const int* __restrict__ pbase,
                             const int* __restrict__ offs, int* __restrict__ csr_src,
                             int N, int NB) {
    __shared__ int lcur[256];
    int b = blockIdx.x, t = threadIdx.x;
    int node = b * 256 + t;
    lcur[t] = (node < N) ? offs[node] : 0;
    __syncthreads();
    for (int blk = t; blk < NBLK; blk += 256) {
        int w0 = pbase[(size_t)blk * NB + b];
        int w1 = pbase[(size_t)blk * NB + b + 1];
        for (int i = w0; i < w1; ++i) {
            int2 p = pairs[i];
            int pos = atomicAdd(&lcur[p.y & 255], 1);
            csr_src[pos] = p.x;
        }
    }
}

// ---- weight convert to fragment-major: Wf[(k>>3)*Nn*8 + n*8 + (k&7)] = bf16(W[k][n]) ----
__global__ void wconv_kernel(const float* __restrict__ W, unsigned short* __restrict__ Wf,
                             int K, int Nn) {
    int i = blockIdx.x * blockDim.x + threadIdx.x;
    if (i >= K * Nn) return;
    int k = i / Nn, n = i - k * Nn;
    Wf[(size_t)(k >> 3) * Nn * 8 + n * 8 + (k & 7)] = f2bf(W[i]);
}

// ---- fused MLP: h = relu(x@W1+b1)@W2+b2 ; out = sigmoid(h.pw+pb)*h ;
//      g0 = bf16(dinv*h).  BM=64 rows/block, 256 thr (4 waves).
// Weights fragment-major in global (coalesced 16B/lane B-loads). ----
__global__ __launch_bounds__(256, 4) void mlp_fused(
        const float* __restrict__ x,
        const unsigned short* __restrict__ W1f,   // frag-major [k>>3][256 n][8]
        const float* __restrict__ b1,
        const unsigned short* __restrict__ W2f,   // frag-major [k>>3][64 n][8]
        const float* __restrict__ b2,
        const float* __restrict__ dinv,
        const float* __restrict__ pw, const float* __restrict__ pb,
        float* __restrict__ out, unsigned short* __restrict__ g,
        int M) {
    __shared__ unsigned short xfrag[4 * RS];    // region = (k&31)>>3
    __shared__ unsigned short h1frag[32 * RS];  // region = ch>>3 (stage-2 k)
    __shared__ float pools[2][2][2][16];        // [rt2][ct2][half][reg]

    int tid = threadIdx.x;
    int wave = tid >> 6, lane = tid & 63;
    int half = lane >> 5, l31 = lane & 31;
    int rt = wave & 1;          // stage-1 row tile (32 rows)
    int cw = wave >> 1;         // stage-1 col half (128 cols)
    int bm = blockIdx.x * 64;

    f32x16 acc1[4] = {};

    float4 xv[2];
    #pragma unroll
    for (int i = 0; i < 2; ++i) {
        int f = i * 256 + tid;
        int row = f >> 3, c4 = (f & 7) * 4;
        int grow = bm + row;
        xv[i] = (grow < M) ? *(const float4*)(x + (size_t)grow * 256 + c4)
                           : make_float4(0.f, 0.f, 0.f, 0.f);
    }

    for (int it = 0; it < 8; ++it) {
        #pragma unroll
        for (int i = 0; i < 2; ++i) {
            int f = i * 256 + tid;
            int row = f >> 3, c4 = (f & 7) * 4;
            int region = c4 >> 3, off = c4 & 7;
            ushort4 u;
            u.x = f2bf(xv[i].x); u.y = f2bf(xv[i].y);
            u.z = f2bf(xv[i].z); u.w = f2bf(xv[i].w);
            *(ushort4*)&xfrag[region * RS + row * 8 + off] = u;
        }
        __syncthreads();
        if (it < 7) {
            int k0 = (it + 1) * 32;
            #pragma unroll
            for (int i = 0; i < 2; ++i) {
                int f = i * 256 + tid;
                int row = f >> 3, c4 = (f & 7) * 4;
                int grow = bm + row;
                xv[i] = (grow < M) ? *(const float4*)(x + (size_t)grow * 256 + k0 + c4)
                                   : make_float4(0.f, 0.f, 0.f, 0.f);
            }
        }
        // MFMAs; B fragments coalesced from global frag-major layout
        #pragma unroll
        for (int s = 0; s < 2; ++s) {
            int region = it * 4 + s * 2 + half;          // k>>3 of this fragment
            bf16x8 a = *(bf16x8*)&xfrag[(s * 2 + half) * RS + (rt * 32 + l31) * 8];
            #pragma unroll
            for (int j = 0; j < 4; ++j) {
                int ch = cw * 128 + j * 32 + l31;
                bf16x8 b = *(const bf16x8*)(W1f + (size_t)region * 2048 + ch * 8);
                acc1[j] = __builtin_amdgcn_mfma_f32_32x32x16_bf16(a, b, acc1[j], 0, 0, 0);
            }
        }
        __syncthreads();
    }

    // bias + relu, write h1 tile to LDS in stage-2 A-fragment layout
    #pragma unroll
    for (int j = 0; j < 4; ++j) {
        int ch = cw * 128 + j * 32 + l31;     // stage-2 k index
        float bb = b1[ch];
        int region = ch >> 3, off = ch & 7;
        #pragma unroll
        for (int reg = 0; reg < 16; ++reg) {
            int rowin = (reg & 3) + 8 * (reg >> 2) + 4 * half;
            int row = rt * 32 + rowin;
            float v = fmaxf(acc1[j][reg] + bb, 0.f);
            h1frag[region * RS + row * 8 + off] = f2bf(v);
        }
    }
    __syncthreads();

    // stage 2 on all 4 waves: wave = rt2*2 + ct2 tile (32 rows x 32 cols)
    int rt2 = wave >> 1, ct2 = wave & 1;
    f32x16 acc2 = {};
    #pragma unroll
    for (int s = 0; s < 16; ++s) {
        bf16x8 a = *(bf16x8*)&h1frag[(s * 2 + half) * RS + (rt2 * 32 + l31) * 8];
        bf16x8 b = *(const bf16x8*)(W2f + (size_t)(s * 2 + half) * 512 + (ct2 * 32 + l31) * 8);
        acc2 = __builtin_amdgcn_mfma_f32_32x32x16_bf16(a, b, acc2, 0, 0, 0);
    }

    // pooling partials: butterfly over 32 cols, pool-exchange across col tiles
    float bb = b2[ct2 * 32 + l31];
    float pwv = pw[ct2 * 32 + l31];
    float pbv = pb[0];
    float hreg[16];
    #pragma unroll
    for (int reg = 0; reg < 16; ++reg) {
        float h = acc2[reg] + bb;
        hreg[reg] = h;
        float d = h * pwv;
        d += __shfl_xor(d, 1, 64);
        d += __shfl_xor(d, 2, 64);
        d += __shfl_xor(d, 4, 64);
        d += __shfl_xor(d, 8, 64);
        d += __shfl_xor(d, 16, 64);
        if (l31 == 0) pools[rt2][ct2][half][reg] = d;
    }
    __syncthreads();
    #pragma unroll
    for (int reg = 0; reg < 16; ++reg) {
        int rowin = (reg & 3) + 8 * (reg >> 2) + 4 * half;
        int row = bm + rt2 * 32 + rowin;
        float d = pools[rt2][0][half][reg] + pools[rt2][1][half][reg];
        float sg = 1.f / (1.f + __expf(-(d + pbv)));
        float h = hreg[reg];
        if (row < M) {
            float dv = dinv[row];
            out[(size_t)row * 64 + ct2 * 32 + l31] = sg * h;
            g[(size_t)row * 64 + ct2 * 32 + l31]   = f2bf(dv * h);
        }
    }
}

// ---- one hop (r11 form): wave per dest; 16 lanes per row (4 ch/lane via uint2),
//      4 edges per gather instruction, 32 edges in flight; fused pooling ----
__global__ void spmm_kernel(const int* __restrict__ offs, const int* __restrict__ src,
                            const float* __restrict__ dinv,
                            const unsigned* __restrict__ gin,      // bf16x2 words, 32/row
                            unsigned short* __restrict__ gout,
                            float* __restrict__ out,
                            const float* __restrict__ pw, const float* __restrict__ pb,
                            int n) {
    int wid = (blockIdx.x * blockDim.x + threadIdx.x) >> 6;
    int lane = threadIdx.x & 63;
    if (wid >= n) return;
    int g = lane >> 4;      // edge slot within a quad (0..3)
    int q = lane & 15;      // word-pair index -> channels 4q..4q+3
    int c = __builtin_amdgcn_readfirstlane(wid);
    int e0   = __builtin_amdgcn_readfirstlane(offs[c]);
    int eend = __builtin_amdgcn_readfirstlane(offs[c + 1]);

    float a0 = 0.f, a1 = 0.f, a2 = 0.f, a3 = 0.f;
    for (int e = e0; e < eend; e += 32) {
        #pragma unroll
        for (int i = 0; i < 8; ++i) {
            int ei = e + i * 4 + g;
            int ec = (ei < eend) ? ei : (eend - 1);   // clamp: pad quads re-read one row
            float m = (ei < eend) ? 1.f : 0.f;
            int s = src[ec];
            uint2 v = *(const uint2*)(gin + (size_t)s * 32 + q * 2);
            a0 = fmaf(m, bflo(v.x), a0);
            a1 = fmaf(m, bfhi(v.x), a1);
            a2 = fmaf(m, bflo(v.y), a2);
            a3 = fmaf(m, bfhi(v.y), a3);
        }
    }

    // reduce across the 4 edge slots (xor 16, 32 stay within channel q)
    a0 += __shfl_xor(a0, 16, 64); a0 += __shfl_xor(a0, 32, 64);
    a1 += __shfl_xor(a1, 16, 64); a1 += __shfl_xor(a1, 32, 64);
    a2 += __shfl_xor(a2, 16, 64); a2 += __shfl_xor(a2, 32, 64);
    a3 += __shfl_xor(a3, 16, 64); a3 += __shfl_xor(a3, 32, 64);

    // self-loop term (gin already prescaled by dinv[src])
    uint2 sv = *(const uint2*)(gin + (size_t)c * 32 + q * 2);
    a0 += bflo(sv.x); a1 += bfhi(sv.x);
    a2 += bflo(sv.y); a3 += bfhi(sv.y);

    float dc = dinv[c];
    float h0 = dc * a0, h1 = dc * a1, h2 = dc * a2, h3 = dc * a3;

    // fused adaptive pooling: d = sum_ch h*pw  (4 per lane, then 16-lane tree)
    float4 pv = *(const float4*)(pw + q * 4);
    float d = h0 * pv.x + h1 * pv.y + h2 * pv.z + h3 * pv.w;
    d += __shfl_xor(d, 1, 64);
    d += __shfl_xor(d, 2, 64);
    d += __shfl_xor(d, 4, 64);
    d += __shfl_xor(d, 8, 64);
    float sg = 1.f / (1.f + __expf(-(d + pb[0])));

    if (g == 0) {
        ushort4 gw;
        gw.x = f2bf(dc * h0); gw.y = f2bf(dc * h1);
        gw.z = f2bf(dc * h2); gw.w = f2bf(dc * h3);
        *(ushort4*)(gout + (size_t)c * 64 + q * 4) = gw;
        float4 o = *(float4*)(out + (size_t)c * 64 + q * 4);
        o.x += sg * h0; o.y += sg * h1; o.z += sg * h2; o.w += sg * h3;
        *(float4*)(out + (size_t)c * 64 + q * 4) = o;
    }
}

extern "C" void kernel_launch(void* const* d_in, const int* in_sizes, int n_in,
                              void* d_out, int out_size, void* d_ws, size_t ws_size,
                              hipStream_t stream) {
    const float* x  = (const float*)d_in[0];
    const int* eidx = (const int*)d_in[1];
    const float* W1 = (const float*)d_in[2];
    const float* b1 = (const float*)d_in[3];
    const float* W2 = (const float*)d_in[4];
    const float* b2 = (const float*)d_in[5];
    const float* pw = (const float*)d_in[6];
    const float* pb = (const float*)d_in[7];
    float* out = (float*)d_out;

    const int N = in_sizes[0] / 256;
    const int E = in_sizes[1] / 2;
    const int NB = (N + 255) >> 8;              // buckets of 256 dest nodes
    const int EPB = (E + NBLK - 1) / NBLK;      // edges per passA/passB block
    const int M = NB * NBLK;                    // blk_cnt entries

    size_t woff = 0;
    auto alloc = [&](size_t bytes) -> void* {
        void* p = (char*)d_ws + woff;
        woff += (bytes + 255) & ~(size_t)255;
        return p;
    };
    int*   sflag   = (int*)alloc(4);
    int*   cnt     = (int*)alloc((size_t)N * 4);
    float* dinv    = (float*)alloc((size_t)N * 4);
    int*   offs    = (int*)alloc(((size_t)N + 1) * 4);
    int*   bsums   = (int*)alloc(1024 * 4);
    int*   bsums2  = (int*)alloc(1024 * 4);
    int*   pbase   = (int*)alloc(((size_t)M + 1) * 4);
    int*   csr_src = (int*)alloc((size_t)E * 4);
    int2*  pairs   = (int2*)alloc((size_t)E * 8);
    unsigned short* W1f = (unsigned short*)alloc((size_t)256 * 256 * 2);
    unsigned short* W2f = (unsigned short*)alloc((size_t)64 * 256 * 2);
    unsigned short* gA = (unsigned short*)alloc((size_t)N * 64 * 2);
    unsigned short* gB = (unsigned short*)alloc((size_t)N * 64 * 2);

    detect_kernel<<<1, 256, 0, stream>>>((const unsigned*)eidx, sflag);

    // build: histogram -> scan -> pair scatter -> node counts(+dinv) -> offs -> CSR
    passA_kernel<<<NBLK, 256, 0, stream>>>(eidx, sflag, pbase, E, NB, EPB);
    int nb2 = (M + 1023) / 1024;
    scan1_kernel<<<nb2, 256, 0, stream>>>(pbase, pbase, bsums2, M);
    scan2g_kernel<<<1, 256, 0, stream>>>(bsums2, nb2);
    scan3_kernel<<<nb2, 256, 0, stream>>>(pbase, bsums2, M, E);
    passB_kernel<<<NBLK, 256, 0, stream>>>(eidx, sflag, pbase, pairs, E, NB, EPB);
    passD_kernel<<<NB, 256, 0, stream>>>(pairs, pbase, cnt, dinv, N, NB);
    int nb1 = (N + 1023) / 1024;
    scan1_kernel<<<nb1, 256, 0, stream>>>(cnt, offs, bsums, N);
    scan2g_kernel<<<1, 256, 0, stream>>>(bsums, nb1);
    scan3_kernel<<<nb1, 256, 0, stream>>>(offs, bsums, N, E);
    passC_kernel<<<NB, 256, 0, stream>>>(pairs, pbase, offs, csr_src, N, NB);

    // MLP (fused) + hop0
    wconv_kernel<<<(256 * 256 + 255) / 256, 256, 0, stream>>>(W1, W1f, 256, 256);
    wconv_kernel<<<(64 * 256 + 255) / 256, 256, 0, stream>>>(W2, W2f, 256, 64);
    int gb = (N + 63) / 64;
    mlp_fused<<<gb, 256, 0, stream>>>(x, W1f, b1, W2f, b2, dinv, pw, pb,
                                      out, gA, N);

    // propagation + fused pooling
    int nwb = (N + 3) / 4;  // 4 waves (=4 dest nodes) per 256-thread block
    unsigned short* gin = gA;
    unsigned short* gout = gB;
    for (int k = 0; k < 10; ++k) {
        spmm_kernel<<<nwb, 256, 0, stream>>>(offs, csr_src, dinv,
                                             (const unsigned*)gin, gout, out, pw, pb, N);
        unsigned short* t = gin; gin = gout; gout = t;
    }
}